// Round 2
// baseline (305.180 us; speedup 1.0000x reference)
//
#include <hip/hip_runtime.h>

// Problem constants
#define BATCH   4
#define SEQ     4096
#define DMODEL  1024
#define HDIM    120
#define NPAD    128                    // HD padded to 128 (zero-filled) for clean K=4x32 MFMA loop
#define ROWS_TOTAL (BATCH * SEQ)       // 16384

typedef float f32x4 __attribute__((ext_vector_type(4)));
typedef float f32x2 __attribute__((ext_vector_type(2)));
typedef short s16x8 __attribute__((ext_vector_type(8)));

static __device__ __forceinline__ unsigned short f2bf(float f) {
    unsigned u = __float_as_uint(f);
    u += 0x7FFFu + ((u >> 16) & 1u);   // round-to-nearest-even
    return (unsigned short)(u >> 16);
}

static __device__ __forceinline__ s16x8 pack8(const float* v) {
    s16x8 r;
#pragma unroll
    for (int i = 0; i < 8; ++i) r[i] = (short)f2bf(v[i]);
    return r;
}

// ---------------------------------------------------------------------------
// Kernel A: context = query @ Wq^T + bq, scaled by weight_tensor, L2-normalized
// rows. Output: ctx_n as bf16 [16384][128], cols 120..127 zero.
// v2: 32 rows/block, 512 threads (8 waves = 2 row-halves x 4 col-quarters),
// grid 512 (2 blocks/CU), LDS double-buffered with ONE barrier per K-step.
// ---------------------------------------------------------------------------
__global__ __launch_bounds__(512)
void ctx_norm_kernel(const float* __restrict__ query,
                     const float* __restrict__ Wq,
                     const float* __restrict__ bq,
                     const float* __restrict__ wt,
                     unsigned short* __restrict__ ctx)
{
    // row stride 40 bf16 (80B): 2-way bank alias only (free per m136)
    __shared__ unsigned short lA[2][32 * 40];
    __shared__ unsigned short lB[2][128 * 40];
    __shared__ float lsq[32 * 4];

    const int tid  = threadIdx.x;
    const int lane = tid & 63;
    const int wv   = tid >> 6;          // 0..7
    const int wr   = wv & 1;            // row half (16 rows)
    const int wc   = wv >> 1;           // col quarter (32 cols)
    const int l15  = lane & 15;
    const int l4   = lane >> 4;
    const int row0 = blockIdx.x * 32;

    // staging assignments (512 threads)
    const int ar = tid >> 4;            // A row 0..31
    const int ak = (tid & 15) * 2;      // A k-offset, 2 floats each
    const int bn = tid >> 2;            // B row 0..127
    const int bk = (tid & 3) * 8;       // B k-offset, 8 floats each

    f32x4 acc[2];
#pragma unroll
    for (int n = 0; n < 2; ++n) acc[n] = (f32x4){0.f, 0.f, 0.f, 0.f};

    auto stage = [&](int buf, int ks) {
        const int k0 = ks * 32;
        // A tile: query[row0+ar][k0+ak .. +2] -> bf16
        {
            const f32x2 av = *(const f32x2*)(query + (size_t)(row0 + ar) * DMODEL + k0 + ak);
            const unsigned pa = (unsigned)f2bf(av.x) | ((unsigned)f2bf(av.y) << 16);
            *(unsigned*)&lA[buf][ar * 40 + ak] = pa;
        }
        // B tile: Wq[bn][k0+bk .. +8] -> bf16 (zero rows >= 120)
        {
            float tmp[8];
            if (bn < HDIM) {
                const float* src = Wq + (size_t)bn * DMODEL + k0 + bk;
                *(f32x4*)(tmp)     = *(const f32x4*)(src);
                *(f32x4*)(tmp + 4) = *(const f32x4*)(src + 4);
            } else {
#pragma unroll
                for (int i = 0; i < 8; ++i) tmp[i] = 0.f;
            }
            *(s16x8*)&lB[buf][bn * 40 + bk] = pack8(tmp);
        }
    };

    stage(0, 0);

    for (int ks = 0; ks < 32; ++ks) {
        __syncthreads();                       // tile ks staged; prev reads done
        if (ks + 1 < 32) stage((ks + 1) & 1, ks + 1);
        const int buf = ks & 1;
        const s16x8 a = *(const s16x8*)&lA[buf][(wr * 16 + l15) * 40 + l4 * 8];
#pragma unroll
        for (int n = 0; n < 2; ++n) {
            const s16x8 bfr = *(const s16x8*)&lB[buf][(wc * 32 + n * 16 + l15) * 40 + l4 * 8];
            acc[n] = __builtin_amdgcn_mfma_f32_16x16x32_bf16(a, bfr, acc[n], 0, 0, 0);
        }
    }

    // epilogue: (acc + bq)*wt, row L2-norm (cross-wave over col quarters), store
    float sumsq[4] = {0.f, 0.f, 0.f, 0.f};
#pragma unroll
    for (int n = 0; n < 2; ++n) {
        const int col = wc * 32 + n * 16 + l15;
        const float bqv = (col < HDIM) ? bq[col] : 0.f;
        const float wvv = (col < HDIM) ? wt[col] : 0.f;
#pragma unroll
        for (int r = 0; r < 4; ++r) {
            const float v = (acc[n][r] + bqv) * wvv;
            acc[n][r] = v;
            sumsq[r] += v * v;
        }
    }
#pragma unroll
    for (int r = 0; r < 4; ++r) {
        float s = sumsq[r];
        s += __shfl_xor(s, 1);
        s += __shfl_xor(s, 2);
        s += __shfl_xor(s, 4);
        s += __shfl_xor(s, 8);
        sumsq[r] = s;
    }
    if (l15 == 0) {
#pragma unroll
        for (int r = 0; r < 4; ++r)
            lsq[(wr * 16 + l4 * 4 + r) * 4 + wc] = sumsq[r];
    }
    __syncthreads();
    float rinv[4];
#pragma unroll
    for (int r = 0; r < 4; ++r) {
        const int lr = wr * 16 + l4 * 4 + r;
        const float s = lsq[lr * 4 + 0] + lsq[lr * 4 + 1] + lsq[lr * 4 + 2] + lsq[lr * 4 + 3];
        rinv[r] = 1.f / fmaxf(sqrtf(s), 1e-12f);
    }
#pragma unroll
    for (int r = 0; r < 4; ++r) {
        const size_t row = (size_t)(row0 + wr * 16 + l4 * 4 + r);
#pragma unroll
        for (int n = 0; n < 2; ++n)
            ctx[row * NPAD + wc * 32 + n * 16 + l15] = f2bf(acc[n][r] * rinv[r]);
    }
}

// ---------------------------------------------------------------------------
// Kernel B: scores = ctx_n @ ctx_n^T (per batch), softmax over cols, fp32 out.
// cosines in [-1,1] -> skip max-subtraction.
// v2: 32 rows/block, 1024 threads = 16 waves (2 row-groups x 8 col-groups of
// 512 cols). Grid 512 -> 2 blocks/CU x 16 waves = 32 waves/CU (100% occupancy
// at VGPR<=64). Two passes over col-tiles (recompute; ctx/batch=1MB L2-hot).
// ---------------------------------------------------------------------------
__global__ __launch_bounds__(1024)
void gram_softmax_kernel(const unsigned short* __restrict__ ctx,
                         float* __restrict__ out)
{
    __shared__ float lsum[32 * 8];      // [local row][col-group]

    const int tid  = threadIdx.x;
    const int lane = tid & 63;
    const int wv   = tid >> 6;          // 0..15
    const int rg   = wv >> 3;           // row-group 0..1 (16 rows each)
    const int cg   = wv & 7;            // col-group 0..7 (512 cols each)
    const int l15  = lane & 15;
    const int l4   = lane >> 4;

    const int b    = blockIdx.x >> 7;
    const int rb   = blockIdx.x & 127;
    const int row0 = rb * 32 + rg * 16;                  // row within batch
    const unsigned short* cb = ctx + (size_t)b * SEQ * NPAD;

    // A fragments: this wave's 16 rows x K=128, registers, reused both passes
    s16x8 afrag[4];
    {
        const unsigned short* ap = cb + (size_t)(row0 + l15) * NPAD + l4 * 8;
#pragma unroll
        for (int ks = 0; ks < 4; ++ks) afrag[ks] = *(const s16x8*)(ap + ks * 32);
    }

    const int col0 = cg * 512;
    float rowsum[4] = {0.f, 0.f, 0.f, 0.f};

    // pass 1: row sums of exp(score)
    for (int t = 0; t < 32; ++t) {
        const unsigned short* bp = cb + (size_t)(col0 + t * 16 + l15) * NPAD + l4 * 8;
        f32x4 acc = (f32x4){0.f, 0.f, 0.f, 0.f};
#pragma unroll
        for (int ks = 0; ks < 4; ++ks) {
            const s16x8 bfr = *(const s16x8*)(bp + ks * 32);
            acc = __builtin_amdgcn_mfma_f32_16x16x32_bf16(afrag[ks], bfr, acc, 0, 0, 0);
        }
#pragma unroll
        for (int j = 0; j < 4; ++j) rowsum[j] += __expf(acc[j]);
    }
    // reduce across the 16 col-lanes of each row
#pragma unroll
    for (int j = 0; j < 4; ++j) {
        float s = rowsum[j];
        s += __shfl_xor(s, 1);
        s += __shfl_xor(s, 2);
        s += __shfl_xor(s, 4);
        s += __shfl_xor(s, 8);
        rowsum[j] = s;
    }
    // reduce across the 8 col-groups via LDS
    if (l15 == 0) {
#pragma unroll
        for (int j = 0; j < 4; ++j)
            lsum[(rg * 16 + l4 * 4 + j) * 8 + cg] = rowsum[j];
    }
    __syncthreads();
    float rinv[4];
#pragma unroll
    for (int j = 0; j < 4; ++j) {
        const int lr = rg * 16 + l4 * 4 + j;
        float s = 0.f;
#pragma unroll
        for (int w = 0; w < 8; ++w) s += lsum[lr * 8 + w];
        rinv[j] = 1.f / s;
    }

    // pass 2: recompute scores, write exp(s) * (1/rowsum)
    float* ob = out + ((size_t)b * SEQ + row0) * SEQ;
    for (int t = 0; t < 32; ++t) {
        const unsigned short* bp = cb + (size_t)(col0 + t * 16 + l15) * NPAD + l4 * 8;
        f32x4 acc = (f32x4){0.f, 0.f, 0.f, 0.f};
#pragma unroll
        for (int ks = 0; ks < 4; ++ks) {
            const s16x8 bfr = *(const s16x8*)(bp + ks * 32);
            acc = __builtin_amdgcn_mfma_f32_16x16x32_bf16(afrag[ks], bfr, acc, 0, 0, 0);
        }
        const int col = col0 + t * 16 + l15;
#pragma unroll
        for (int j = 0; j < 4; ++j) {
            ob[(size_t)(l4 * 4 + j) * SEQ + col] = __expf(acc[j]) * rinv[j];
        }
    }
}

extern "C" void kernel_launch(void* const* d_in, const int* in_sizes, int n_in,
                              void* d_out, int out_size, void* d_ws, size_t ws_size,
                              hipStream_t stream)
{
    const float* query = (const float*)d_in[0];
    // d_in[1] = key (unused by the forward)
    const float* Wq    = (const float*)d_in[2];
    const float* bq    = (const float*)d_in[3];
    const float* wt    = (const float*)d_in[4];
    float* out = (float*)d_out;
    unsigned short* ctx = (unsigned short*)d_ws;   // 16384*128*2 = 4 MiB scratch

    ctx_norm_kernel<<<dim3(ROWS_TOTAL / 32), dim3(512), 0, stream>>>(query, Wq, bq, wt, ctx);
    gram_softmax_kernel<<<dim3(BATCH * (SEQ / 32)), dim3(1024), 0, stream>>>(ctx, out);
}

// Round 3
// 224.581 us; speedup vs baseline: 1.3589x; 1.3589x over previous
//
#include <hip/hip_runtime.h>

// Problem constants
#define BATCH   4
#define SEQ     4096
#define DMODEL  1024
#define HDIM    120
#define NPAD    128                    // HD padded to 128 for clean K=4x32 MFMA loop
#define ROWS_TOTAL (BATCH * SEQ)       // 16384

typedef float f32x4 __attribute__((ext_vector_type(4)));
typedef short s16x8 __attribute__((ext_vector_type(8)));

static __device__ __forceinline__ unsigned short f2bf(float f) {
    unsigned u = __float_as_uint(f);
    u += 0x7FFFu + ((u >> 16) & 1u);   // round-to-nearest-even
    return (unsigned short)(u >> 16);
}

static __device__ __forceinline__ s16x8 pack2x4(f32x4 lo, f32x4 hi) {
    s16x8 r;
#pragma unroll
    for (int i = 0; i < 4; ++i) r[i] = (short)f2bf(lo[i]);
#pragma unroll
    for (int i = 0; i < 4; ++i) r[4 + i] = (short)f2bf(hi[i]);
    return r;
}

// ---------------------------------------------------------------------------
// Kernel A: context = query @ Wq^T + bq, scaled by weight_tensor, L2-normalized
// rows -> ctx bf16 [16384][128] (cols 120..127 zero).
// v3: NO LDS staging. 512 threads = 8 waves (2 row-halves x 4 col-quarters),
// 32 rows/block. Each lane loads its MFMA fragments (8 contiguous floats)
// straight from global (Wq 480KB is L2-resident; query x4 redundancy ~ 8us of
// L2), raw regs double-buffered, zero barriers in the K-loop.
// ---------------------------------------------------------------------------
struct RawAB { f32x4 a[2]; f32x4 b[2][2]; };

__global__ __launch_bounds__(512)
void ctx_norm_kernel(const float* __restrict__ query,
                     const float* __restrict__ Wq,
                     const float* __restrict__ bq,
                     const float* __restrict__ wt,
                     unsigned short* __restrict__ ctx)
{
    __shared__ float lsq[32 * 4];

    const int tid  = threadIdx.x;
    const int lane = tid & 63;
    const int wv   = tid >> 6;          // 0..7
    const int wr   = wv & 1;            // row half (16 rows)
    const int wc   = wv >> 1;           // col quarter (32 cols = 2 MFMA tiles)
    const int l15  = lane & 15;
    const int l4   = lane >> 4;
    const int row0 = blockIdx.x * 32;

    // per-lane fragment sources: 8 contiguous k's at k0 + l4*8
    const float* aptr = query + (size_t)(row0 + wr * 16 + l15) * DMODEL + l4 * 8;
    const int c0 = wc * 32 + l15;            // n=0 col
    const int c1 = c0 + 16;                  // n=1 col
    const float* bptr0 = Wq + (size_t)(c0 < HDIM ? c0 : HDIM - 1) * DMODEL + l4 * 8;
    const float* bptr1 = Wq + (size_t)(c1 < HDIM ? c1 : HDIM - 1) * DMODEL + l4 * 8;

    f32x4 acc[2];
#pragma unroll
    for (int n = 0; n < 2; ++n) acc[n] = (f32x4){0.f, 0.f, 0.f, 0.f};

    auto load_raw = [&](RawAB& r, int ks) {
        const int k0 = ks * 32;
        r.a[0] = *(const f32x4*)(aptr + k0);
        r.a[1] = *(const f32x4*)(aptr + k0 + 4);
        r.b[0][0] = *(const f32x4*)(bptr0 + k0);
        r.b[0][1] = *(const f32x4*)(bptr0 + k0 + 4);
        r.b[1][0] = *(const f32x4*)(bptr1 + k0);
        r.b[1][1] = *(const f32x4*)(bptr1 + k0 + 4);
    };
    auto compute = [&](const RawAB& r) {
        const s16x8 a = pack2x4(r.a[0], r.a[1]);
#pragma unroll
        for (int n = 0; n < 2; ++n) {
            const s16x8 bfr = pack2x4(r.b[n][0], r.b[n][1]);
            acc[n] = __builtin_amdgcn_mfma_f32_16x16x32_bf16(a, bfr, acc[n], 0, 0, 0);
        }
    };

    RawAB r0, r1;
    load_raw(r0, 0);
    for (int ks = 0; ks < 32; ks += 2) {
        load_raw(r1, ks + 1 < 32 ? ks + 1 : 31);
        compute(r0);
        load_raw(r0, ks + 2 < 32 ? ks + 2 : 31);
        compute(r1);
    }

    // epilogue: (acc + bq)*wt, row L2-norm (cross-wave over col quarters), store
    float sumsq[4] = {0.f, 0.f, 0.f, 0.f};
#pragma unroll
    for (int n = 0; n < 2; ++n) {
        const int col = wc * 32 + n * 16 + l15;
        const float bqv = (col < HDIM) ? bq[col] : 0.f;
        const float wvv = (col < HDIM) ? wt[col] : 0.f;   // wvv=0 zeroes pad cols
#pragma unroll
        for (int r = 0; r < 4; ++r) {
            const float v = (acc[n][r] + bqv) * wvv;
            acc[n][r] = v;
            sumsq[r] += v * v;
        }
    }
#pragma unroll
    for (int r = 0; r < 4; ++r) {
        float s = sumsq[r];
        s += __shfl_xor(s, 1);
        s += __shfl_xor(s, 2);
        s += __shfl_xor(s, 4);
        s += __shfl_xor(s, 8);
        sumsq[r] = s;
    }
    if (l15 == 0) {
#pragma unroll
        for (int r = 0; r < 4; ++r)
            lsq[(wr * 16 + l4 * 4 + r) * 4 + wc] = sumsq[r];
    }
    __syncthreads();
#pragma unroll
    for (int r = 0; r < 4; ++r) {
        const int lr = wr * 16 + l4 * 4 + r;
        const float s = lsq[lr * 4 + 0] + lsq[lr * 4 + 1] + lsq[lr * 4 + 2] + lsq[lr * 4 + 3];
        const float rinv = 1.f / fmaxf(sqrtf(s), 1e-12f);
        const size_t row = (size_t)(row0 + lr);
#pragma unroll
        for (int n = 0; n < 2; ++n)
            ctx[row * NPAD + wc * 32 + n * 16 + l15] = f2bf(acc[n][r] * rinv);
    }
}

// ---------------------------------------------------------------------------
// Kernel B: scores = ctx_n @ ctx_n^T (per batch), softmax over cols, fp32 out.
// cosines in [-1,1] -> skip max-subtraction.
// v3: 512 threads = 8 waves; block owns 32 rows x 4096 cols; each wave = one
// 512-col group, TWO independent row-block MFMA chains, register-double-
// buffered B fragments with prefetch issued BEFORE stores (so the load->MFMA
// waitcnt never drains the store queue). XCD-swizzled blockIdx.
// ---------------------------------------------------------------------------
__global__ __launch_bounds__(512)
void gram_softmax_kernel(const unsigned short* __restrict__ ctx,
                         float* __restrict__ out)
{
    __shared__ float lsum[32 * 8];      // [local row][col-group]

    const int tid  = threadIdx.x;
    const int lane = tid & 63;
    const int cg   = tid >> 6;          // col-group 0..7 (512 cols each)
    const int l15  = lane & 15;
    const int l4   = lane >> 4;

    // XCD-aware swizzle: 512 blocks, 8 XCDs -> each XCD gets 64 contiguous
    const int swz  = (blockIdx.x & 7) * 64 + (blockIdx.x >> 3);
    const int b    = swz >> 7;          // batch
    const int rb   = swz & 127;         // row-group within batch
    const int row0 = rb * 32;
    const unsigned short* cb = ctx + (size_t)b * SEQ * NPAD;

    // A fragments: 32 rows (2 row-blocks) x K=128, registers, both passes
    s16x8 afrag[2][4];
#pragma unroll
    for (int r = 0; r < 2; ++r) {
        const unsigned short* ap = cb + (size_t)(row0 + r * 16 + l15) * NPAD + l4 * 8;
#pragma unroll
        for (int ks = 0; ks < 4; ++ks) afrag[r][ks] = *(const s16x8*)(ap + ks * 32);
    }

    const int col0 = cg * 512;
    const unsigned short* bbase = cb + (size_t)(col0 + l15) * NPAD + l4 * 8;

    auto loadB = [&](s16x8* bf, int t) {
        const unsigned short* bp = bbase + (size_t)t * 16 * NPAD;
#pragma unroll
        for (int ks = 0; ks < 4; ++ks) bf[ks] = *(const s16x8*)(bp + ks * 32);
    };

    float rowsum[2][4] = {{0.f,0.f,0.f,0.f},{0.f,0.f,0.f,0.f}};

    auto accum = [&](const s16x8* bf) {
        f32x4 a0 = (f32x4){0.f,0.f,0.f,0.f};
        f32x4 a1 = (f32x4){0.f,0.f,0.f,0.f};
#pragma unroll
        for (int ks = 0; ks < 4; ++ks) {
            a0 = __builtin_amdgcn_mfma_f32_16x16x32_bf16(afrag[0][ks], bf[ks], a0, 0, 0, 0);
            a1 = __builtin_amdgcn_mfma_f32_16x16x32_bf16(afrag[1][ks], bf[ks], a1, 0, 0, 0);
        }
#pragma unroll
        for (int j = 0; j < 4; ++j) {
            rowsum[0][j] += __expf(a0[j]);
            rowsum[1][j] += __expf(a1[j]);
        }
    };

    s16x8 bc[4], bn[4];
    // pass 1: row sums of exp(score)
    loadB(bc, 0);
    for (int t = 0; t < 32; t += 2) {
        loadB(bn, t + 1 < 32 ? t + 1 : 31);
        accum(bc);
        loadB(bc, t + 2 < 32 ? t + 2 : 31);
        accum(bn);
    }

    // reduce across the 16 col-lanes of each row
#pragma unroll
    for (int r = 0; r < 2; ++r)
#pragma unroll
    for (int j = 0; j < 4; ++j) {
        float s = rowsum[r][j];
        s += __shfl_xor(s, 1);
        s += __shfl_xor(s, 2);
        s += __shfl_xor(s, 4);
        s += __shfl_xor(s, 8);
        rowsum[r][j] = s;
    }
    // reduce across the 8 col-groups via LDS
    if (l15 == 0) {
#pragma unroll
        for (int r = 0; r < 2; ++r)
#pragma unroll
        for (int j = 0; j < 4; ++j)
            lsum[(r * 16 + l4 * 4 + j) * 8 + cg] = rowsum[r][j];
    }
    __syncthreads();
    float rinv[2][4];
#pragma unroll
    for (int r = 0; r < 2; ++r)
#pragma unroll
    for (int j = 0; j < 4; ++j) {
        const int lr = r * 16 + l4 * 4 + j;
        float s = 0.f;
#pragma unroll
        for (int w = 0; w < 8; ++w) s += lsum[lr * 8 + w];
        rinv[r][j] = 1.f / s;
    }

    // pass 2: recompute scores, write exp(s) * (1/rowsum).
    // loads for the NEXT tile are issued before this tile's stores.
    float* ob = out + ((size_t)b * SEQ + row0) * SEQ;
    auto storeT = [&](const s16x8* bf, int t) {
        f32x4 a0 = (f32x4){0.f,0.f,0.f,0.f};
        f32x4 a1 = (f32x4){0.f,0.f,0.f,0.f};
#pragma unroll
        for (int ks = 0; ks < 4; ++ks) {
            a0 = __builtin_amdgcn_mfma_f32_16x16x32_bf16(afrag[0][ks], bf[ks], a0, 0, 0, 0);
            a1 = __builtin_amdgcn_mfma_f32_16x16x32_bf16(afrag[1][ks], bf[ks], a1, 0, 0, 0);
        }
        const int col = col0 + t * 16 + l15;
#pragma unroll
        for (int j = 0; j < 4; ++j) {
            ob[(size_t)(l4 * 4 + j) * SEQ + col]      = __expf(a0[j]) * rinv[0][j];
            ob[(size_t)(16 + l4 * 4 + j) * SEQ + col] = __expf(a1[j]) * rinv[1][j];
        }
    };

    loadB(bc, 0);
    for (int t = 0; t < 32; t += 2) {
        loadB(bn, t + 1 < 32 ? t + 1 : 31);
        storeT(bc, t);
        loadB(bc, t + 2 < 32 ? t + 2 : 31);
        storeT(bn, t + 1);
    }
}

extern "C" void kernel_launch(void* const* d_in, const int* in_sizes, int n_in,
                              void* d_out, int out_size, void* d_ws, size_t ws_size,
                              hipStream_t stream)
{
    const float* query = (const float*)d_in[0];
    // d_in[1] = key (unused by the forward)
    const float* Wq    = (const float*)d_in[2];
    const float* bq    = (const float*)d_in[3];
    const float* wt    = (const float*)d_in[4];
    float* out = (float*)d_out;
    unsigned short* ctx = (unsigned short*)d_ws;   // 16384*128*2 = 4 MiB scratch

    ctx_norm_kernel<<<dim3(ROWS_TOTAL / 32), dim3(512), 0, stream>>>(query, Wq, bq, wt, ctx);
    gram_softmax_kernel<<<dim3(BATCH * (SEQ / 32)), dim3(512), 0, stream>>>(ctx, out);
}

// Round 4
// 224.139 us; speedup vs baseline: 1.3616x; 1.0020x over previous
//
#include <hip/hip_runtime.h>

// Problem constants
#define BATCH   4
#define SEQ     4096
#define DMODEL  1024
#define HDIM    120
#define NPAD    128                    // HD padded to 128 for clean K=4x32 MFMA loop
#define ROWS_TOTAL (BATCH * SEQ)       // 16384

typedef float f32x4 __attribute__((ext_vector_type(4)));
typedef short s16x8 __attribute__((ext_vector_type(8)));

static __device__ __forceinline__ unsigned short f2bf(float f) {
    unsigned u = __float_as_uint(f);
    u += 0x7FFFu + ((u >> 16) & 1u);   // round-to-nearest-even
    return (unsigned short)(u >> 16);
}

static __device__ __forceinline__ s16x8 pack2x4(f32x4 lo, f32x4 hi) {
    s16x8 r;
#pragma unroll
    for (int i = 0; i < 4; ++i) r[i] = (short)f2bf(lo[i]);
#pragma unroll
    for (int i = 0; i < 4; ++i) r[4 + i] = (short)f2bf(hi[i]);
    return r;
}

// ---------------------------------------------------------------------------
// Kernel A: context = query @ Wq^T + bq, scaled by weight_tensor, L2-normalized
// rows -> ctx bf16 [16384][128] (cols 120..127 zero).
// 512 threads = 8 waves (2 row-halves x 4 col-quarters), 32 rows/block.
// No LDS staging: per-lane fragments straight from global (Wq L2-resident),
// raw regs double-buffered, zero barriers in the K-loop.
// ---------------------------------------------------------------------------
struct RawAB { f32x4 a[2]; f32x4 b[2][2]; };

__global__ __launch_bounds__(512)
void ctx_norm_kernel(const float* __restrict__ query,
                     const float* __restrict__ Wq,
                     const float* __restrict__ bq,
                     const float* __restrict__ wt,
                     unsigned short* __restrict__ ctx)
{
    __shared__ float lsq[32 * 4];

    const int tid  = threadIdx.x;
    const int lane = tid & 63;
    const int wv   = tid >> 6;          // 0..7
    const int wr   = wv & 1;            // row half (16 rows)
    const int wc   = wv >> 1;           // col quarter (32 cols = 2 MFMA tiles)
    const int l15  = lane & 15;
    const int l4   = lane >> 4;
    const int row0 = blockIdx.x * 32;

    const float* aptr = query + (size_t)(row0 + wr * 16 + l15) * DMODEL + l4 * 8;
    const int c0 = wc * 32 + l15;
    const int c1 = c0 + 16;
    const float* bptr0 = Wq + (size_t)(c0 < HDIM ? c0 : HDIM - 1) * DMODEL + l4 * 8;
    const float* bptr1 = Wq + (size_t)(c1 < HDIM ? c1 : HDIM - 1) * DMODEL + l4 * 8;

    f32x4 acc[2];
#pragma unroll
    for (int n = 0; n < 2; ++n) acc[n] = (f32x4){0.f, 0.f, 0.f, 0.f};

    auto load_raw = [&](RawAB& r, int ks) {
        const int k0 = ks * 32;
        r.a[0] = *(const f32x4*)(aptr + k0);
        r.a[1] = *(const f32x4*)(aptr + k0 + 4);
        r.b[0][0] = *(const f32x4*)(bptr0 + k0);
        r.b[0][1] = *(const f32x4*)(bptr0 + k0 + 4);
        r.b[1][0] = *(const f32x4*)(bptr1 + k0);
        r.b[1][1] = *(const f32x4*)(bptr1 + k0 + 4);
    };
    auto compute = [&](const RawAB& r) {
        const s16x8 a = pack2x4(r.a[0], r.a[1]);
#pragma unroll
        for (int n = 0; n < 2; ++n) {
            const s16x8 bfr = pack2x4(r.b[n][0], r.b[n][1]);
            acc[n] = __builtin_amdgcn_mfma_f32_16x16x32_bf16(a, bfr, acc[n], 0, 0, 0);
        }
    };

    RawAB r0, r1;
    load_raw(r0, 0);
    for (int ks = 0; ks < 32; ks += 2) {
        load_raw(r1, ks + 1 < 32 ? ks + 1 : 31);
        compute(r0);
        load_raw(r0, ks + 2 < 32 ? ks + 2 : 31);
        compute(r1);
    }

    // epilogue: (acc + bq)*wt, row L2-norm (cross-wave over col quarters), store
    float sumsq[4] = {0.f, 0.f, 0.f, 0.f};
#pragma unroll
    for (int n = 0; n < 2; ++n) {
        const int col = wc * 32 + n * 16 + l15;
        const float bqv = (col < HDIM) ? bq[col] : 0.f;
        const float wvv = (col < HDIM) ? wt[col] : 0.f;   // wvv=0 zeroes pad cols
#pragma unroll
        for (int r = 0; r < 4; ++r) {
            const float v = (acc[n][r] + bqv) * wvv;
            acc[n][r] = v;
            sumsq[r] += v * v;
        }
    }
#pragma unroll
    for (int r = 0; r < 4; ++r) {
        float s = sumsq[r];
        s += __shfl_xor(s, 1);
        s += __shfl_xor(s, 2);
        s += __shfl_xor(s, 4);
        s += __shfl_xor(s, 8);
        sumsq[r] = s;
    }
    if (l15 == 0) {
#pragma unroll
        for (int r = 0; r < 4; ++r)
            lsq[(wr * 16 + l4 * 4 + r) * 4 + wc] = sumsq[r];
    }
    __syncthreads();
#pragma unroll
    for (int r = 0; r < 4; ++r) {
        const int lr = wr * 16 + l4 * 4 + r;
        const float s = lsq[lr * 4 + 0] + lsq[lr * 4 + 1] + lsq[lr * 4 + 2] + lsq[lr * 4 + 3];
        const float rinv = 1.f / fmaxf(sqrtf(s), 1e-12f);
        const size_t row = (size_t)(row0 + lr);
#pragma unroll
        for (int n = 0; n < 2; ++n)
            ctx[row * NPAD + wc * 32 + n * 16 + l15] = f2bf(acc[n][r] * rinv);
    }
}

// ---------------------------------------------------------------------------
// Kernel B: scores = ctx_n @ ctx_n^T (per batch), softmax over cols, fp32 out.
// cosines in [-1,1] -> skip max-subtraction.
// v4: NON-TEMPORAL output stores (nt flag) so the 256MiB write stream does not
// allocate/evict in L2 -> ctx (4MiB) stays L2-resident -> B-frag loads are L2
// hits, hidden by 2-deep register prefetch + 4 waves/SIMD.
// __launch_bounds__(512,4) caps VGPR at 128 -> guaranteed 16 waves/CU.
// ---------------------------------------------------------------------------
__global__ __launch_bounds__(512, 4)
void gram_softmax_kernel(const unsigned short* __restrict__ ctx,
                         float* __restrict__ out)
{
    __shared__ float lsum[32 * 8];      // [local row][col-group]

    const int tid  = threadIdx.x;
    const int lane = tid & 63;
    const int cg   = tid >> 6;          // col-group 0..7 (512 cols each)
    const int l15  = lane & 15;
    const int l4   = lane >> 4;

    // XCD-aware swizzle: 512 blocks, 8 XCDs -> each XCD gets 64 contiguous
    const int swz  = (blockIdx.x & 7) * 64 + (blockIdx.x >> 3);
    const int b    = swz >> 7;          // batch
    const int rb   = swz & 127;         // row-group within batch
    const int row0 = rb * 32;
    const unsigned short* cb = ctx + (size_t)b * SEQ * NPAD;

    // A fragments: 32 rows (2 row-blocks) x K=128, registers, both passes
    s16x8 afrag[2][4];
#pragma unroll
    for (int r = 0; r < 2; ++r) {
        const unsigned short* ap = cb + (size_t)(row0 + r * 16 + l15) * NPAD + l4 * 8;
#pragma unroll
        for (int ks = 0; ks < 4; ++ks) afrag[r][ks] = *(const s16x8*)(ap + ks * 32);
    }

    const int col0 = cg * 512;
    const unsigned short* bbase = cb + (size_t)(col0 + l15) * NPAD + l4 * 8;

    auto loadB = [&](s16x8* bf, int t) {
        const unsigned short* bp = bbase + (size_t)t * 16 * NPAD;
#pragma unroll
        for (int ks = 0; ks < 4; ++ks) bf[ks] = *(const s16x8*)(bp + ks * 32);
    };

    float rowsum[2][4] = {{0.f,0.f,0.f,0.f},{0.f,0.f,0.f,0.f}};

    auto accum = [&](const s16x8* bf) {
        f32x4 a0 = (f32x4){0.f,0.f,0.f,0.f};
        f32x4 a1 = (f32x4){0.f,0.f,0.f,0.f};
#pragma unroll
        for (int ks = 0; ks < 4; ++ks) {
            a0 = __builtin_amdgcn_mfma_f32_16x16x32_bf16(afrag[0][ks], bf[ks], a0, 0, 0, 0);
            a1 = __builtin_amdgcn_mfma_f32_16x16x32_bf16(afrag[1][ks], bf[ks], a1, 0, 0, 0);
        }
#pragma unroll
        for (int j = 0; j < 4; ++j) {
            rowsum[0][j] += __expf(a0[j]);
            rowsum[1][j] += __expf(a1[j]);
        }
    };

    s16x8 bc[4], bn[4];
    // pass 1: row sums of exp(score)
    loadB(bc, 0);
    for (int t = 0; t < 32; t += 2) {
        loadB(bn, t + 1 < 32 ? t + 1 : 31);
        accum(bc);
        loadB(bc, t + 2 < 32 ? t + 2 : 31);
        accum(bn);
    }

    // reduce across the 16 col-lanes of each row
#pragma unroll
    for (int r = 0; r < 2; ++r)
#pragma unroll
    for (int j = 0; j < 4; ++j) {
        float s = rowsum[r][j];
        s += __shfl_xor(s, 1);
        s += __shfl_xor(s, 2);
        s += __shfl_xor(s, 4);
        s += __shfl_xor(s, 8);
        rowsum[r][j] = s;
    }
    // reduce across the 8 col-groups via LDS
    if (l15 == 0) {
#pragma unroll
        for (int r = 0; r < 2; ++r)
#pragma unroll
        for (int j = 0; j < 4; ++j)
            lsum[(r * 16 + l4 * 4 + j) * 8 + cg] = rowsum[r][j];
    }
    __syncthreads();
    float rinv[2][4];
#pragma unroll
    for (int r = 0; r < 2; ++r)
#pragma unroll
    for (int j = 0; j < 4; ++j) {
        const int lr = r * 16 + l4 * 4 + j;
        float s = 0.f;
#pragma unroll
        for (int w = 0; w < 8; ++w) s += lsum[lr * 8 + w];
        rinv[r][j] = 1.f / s;
    }

    // pass 2: recompute scores, write exp(s)*(1/rowsum) with NT stores
    float* ob = out + ((size_t)b * SEQ + row0) * SEQ;
    auto storeT = [&](const s16x8* bf, int t) {
        f32x4 a0 = (f32x4){0.f,0.f,0.f,0.f};
        f32x4 a1 = (f32x4){0.f,0.f,0.f,0.f};
#pragma unroll
        for (int ks = 0; ks < 4; ++ks) {
            a0 = __builtin_amdgcn_mfma_f32_16x16x32_bf16(afrag[0][ks], bf[ks], a0, 0, 0, 0);
            a1 = __builtin_amdgcn_mfma_f32_16x16x32_bf16(afrag[1][ks], bf[ks], a1, 0, 0, 0);
        }
        const int col = col0 + t * 16 + l15;
#pragma unroll
        for (int j = 0; j < 4; ++j) {
            __builtin_nontemporal_store(__expf(a0[j]) * rinv[0][j],
                                        &ob[(size_t)(l4 * 4 + j) * SEQ + col]);
            __builtin_nontemporal_store(__expf(a1[j]) * rinv[1][j],
                                        &ob[(size_t)(16 + l4 * 4 + j) * SEQ + col]);
        }
    };

    loadB(bc, 0);
    for (int t = 0; t < 32; t += 2) {
        loadB(bn, t + 1 < 32 ? t + 1 : 31);
        storeT(bc, t);
        loadB(bc, t + 2 < 32 ? t + 2 : 31);
        storeT(bn, t + 1);
    }
}

extern "C" void kernel_launch(void* const* d_in, const int* in_sizes, int n_in,
                              void* d_out, int out_size, void* d_ws, size_t ws_size,
                              hipStream_t stream)
{
    const float* query = (const float*)d_in[0];
    // d_in[1] = key (unused by the forward)
    const float* Wq    = (const float*)d_in[2];
    const float* bq    = (const float*)d_in[3];
    const float* wt    = (const float*)d_in[4];
    float* out = (float*)d_out;
    unsigned short* ctx = (unsigned short*)d_ws;   // 16384*128*2 = 4 MiB scratch

    ctx_norm_kernel<<<dim3(ROWS_TOTAL / 32), dim3(512), 0, stream>>>(query, Wq, bq, wt, ctx);
    gram_softmax_kernel<<<dim3(BATCH * (SEQ / 32)), dim3(512), 0, stream>>>(ctx, out);
}